// Round 19
// baseline (229.359 us; speedup 1.0000x reference)
//
#include <hip/hip_runtime.h>

typedef short short8 __attribute__((ext_vector_type(8)));
typedef short short4v __attribute__((ext_vector_type(4)));
typedef float f32x4 __attribute__((ext_vector_type(4)));
typedef unsigned uint2v __attribute__((ext_vector_type(2)));

__device__ __forceinline__ float bf2f(short b) {
  unsigned u = ((unsigned)(unsigned short)b) << 16;
  return __builtin_bit_cast(float, u);
}
__device__ __forceinline__ short f2bf(float f) {
  unsigned u = __builtin_bit_cast(unsigned, f);
  u += 0x7fffu + ((u >> 16) & 1u);
  return (short)(u >> 16);
}
__device__ __forceinline__ unsigned cvt_pk_bf16(float lo, float hi) {
  unsigned r;
  asm("v_cvt_pk_bf16_f32 %0, %1, %2" : "=v"(r) : "v"(lo), "v"(hi));
  return r;
}

__device__ __forceinline__ void gload_lds16(const void* g, void* l) {
  __builtin_amdgcn_global_load_lds(
      (const __attribute__((address_space(1))) unsigned int*)g,
      (__attribute__((address_space(3))) unsigned int*)l, 16, 0, 0);
}

// swizzled LDS fragment read: tile rows of 64 shorts (128B), chunk = 16B unit,
// physical chunk = logical chunk ^ (row & 7)  [T2 involution]
__device__ __forceinline__ short8 lds_frag(const short* tile, int row, int kc, int l4) {
  int chunk = (kc * 4 + l4) ^ (row & 7);
  return *(const short8*)&tile[row * 64 + chunk * 8];
}

// ---------------- fp32 -> bf16 convert (x) ----------------
__global__ __launch_bounds__(256) void k_convert_bf16(const float* __restrict__ in,
                                                      short* __restrict__ out, int n8) {
  int i = blockIdx.x * 256 + threadIdx.x;
  if (i >= n8) return;
  const float4* p = (const float4*)in;
  float4 a = p[2 * i], b = p[2 * i + 1];
  short8 o;
  o[0] = f2bf(a.x); o[1] = f2bf(a.y); o[2] = f2bf(a.z); o[3] = f2bf(a.w);
  o[4] = f2bf(b.x); o[5] = f2bf(b.y); o[6] = f2bf(b.z); o[7] = f2bf(b.w);
  ((short8*)out)[i] = o;
}

// ---------------- weight transpose+convert: w[K][N] f32 -> wT[N][K] bf16 ----------------
__global__ __launch_bounds__(256) void k_transpose_w(const float* __restrict__ w,
                                                     short* __restrict__ wT, int K, int N) {
  __shared__ float t[32][33];
  int nt = N >> 5;
  int rt = blockIdx.x / nt, ct = blockIdx.x % nt;
  int tx = threadIdx.x & 31, ty = threadIdx.x >> 5;
#pragma unroll
  for (int i = 0; i < 4; ++i) {
    int r = ty * 4 + i;
    t[r][tx] = w[(size_t)(rt * 32 + r) * N + ct * 32 + tx];
  }
  __syncthreads();
#pragma unroll
  for (int i = 0; i < 4; ++i) {
    int r = ty * 4 + i;
    wT[(size_t)(ct * 32 + r) * K + rt * 32 + tx] = f2bf(t[tx][r]);
  }
}

// ---------------- GEMM 256x128, BK=64, TWO phases/K-tile (16 MFMA each) [r18 verified] ----------------
template <bool BF16OUT>
__global__ __launch_bounds__(512, 1) void k_gemm8p(const short* __restrict__ A,
                                                   const short* __restrict__ Bt,
                                                   const float* __restrict__ bias,
                                                   void* __restrict__ Cout,
                                                   short* __restrict__ vTout,
                                                   int M, int N, int K) {
  __shared__ __align__(16) short Ab[2][256 * 64];
  __shared__ __align__(16) short Bb[2][128 * 64];
  int nt = N >> 7;
  int nwg = gridDim.x;
  int bid = blockIdx.x;
  int swz = (bid & 7) * (nwg >> 3) + (bid >> 3);  // nwg % 8 == 0 -> bijective
  int mt = swz / nt, ct = swz % nt;
  int tid = threadIdx.x, w = tid >> 6, lane = tid & 63;
  int l15 = lane & 15, l4 = lane >> 4;
  int wm = w >> 2, wn = w & 3;
  const short* Abase = A + (size_t)mt * 256 * K;
  const short* Bbase = Bt + (size_t)ct * 128 * K;
  int NT = K >> 6;

  int srow = lane >> 3;
  int slc = (lane & 7) ^ srow;

  auto stage = [&](const short* gbase, short* dstTile, int kt, int half) {
#pragma unroll
    for (int i = 0; i < 2; ++i) {
      int rowg = half * 128 + i * 64 + w * 8;
      gload_lds16(gbase + (size_t)(rowg + srow) * K + kt * 64 + slc * 8,
                  dstTile + (size_t)rowg * 64);
    }
  };

  f32x4 acc[8][2];
#pragma unroll
  for (int m = 0; m < 8; ++m)
#pragma unroll
    for (int n = 0; n < 2; ++n) acc[m][n] = f32x4{0.f, 0.f, 0.f, 0.f};

  stage(Bbase, &Bb[0][0], 0, 0);
  stage(Abase, &Ab[0][0], 0, 0);
  stage(Abase, &Ab[0][0], 0, 1);
  stage(Bbase, &Bb[1][0], 1, 0);
  stage(Abase, &Ab[1][0], 1, 0);
  asm volatile("s_waitcnt vmcnt(6)" ::: "memory");
  __builtin_amdgcn_s_barrier();

  for (int t = 0; t < NT; ++t) {
    int b = t & 1;
    const short* At = &Ab[b][0];
    const short* Btl = &Bb[b][0];
    bool p1 = (t + 1 < NT), p2 = (t + 2 < NT);

    short8 alo[4][2], ahi[4][2], bfr[2][2];

    // ===== phase 1: m-lo x n (B cached for ph2); stage A-hi(t+1) =====
#pragma unroll
    for (int mq = 0; mq < 4; ++mq)
#pragma unroll
      for (int kc = 0; kc < 2; ++kc)
        alo[mq][kc] = lds_frag(At, wm * 128 + mq * 16 + l15, kc, l4);
#pragma unroll
    for (int n = 0; n < 2; ++n)
#pragma unroll
      for (int kc = 0; kc < 2; ++kc)
        bfr[n][kc] = lds_frag(Btl, wn * 32 + n * 16 + l15, kc, l4);
    if (p1) stage(Abase, &Ab[(t + 1) & 1][0], t + 1, 1);
    __builtin_amdgcn_s_barrier();
    asm volatile("s_waitcnt lgkmcnt(0)" ::: "memory");
    __builtin_amdgcn_sched_barrier(0);
    __builtin_amdgcn_s_setprio(1);
#pragma unroll
    for (int mq = 0; mq < 4; ++mq)
#pragma unroll
      for (int n = 0; n < 2; ++n)
#pragma unroll
        for (int kc = 0; kc < 2; ++kc)
          acc[mq][n] = __builtin_amdgcn_mfma_f32_16x16x32_bf16(alo[mq][kc], bfr[n][kc], acc[mq][n], 0, 0, 0);
    __builtin_amdgcn_s_setprio(0);
    if (p1) {
      asm volatile("s_waitcnt vmcnt(6)" ::: "memory");
    } else {
      asm volatile("s_waitcnt vmcnt(0)" ::: "memory");
    }
    __builtin_amdgcn_s_barrier();

    // ===== phase 2: m-hi x n (B from regs); stage B(t+2) + A-lo(t+2) =====
#pragma unroll
    for (int mq = 0; mq < 4; ++mq)
#pragma unroll
      for (int kc = 0; kc < 2; ++kc)
        ahi[mq][kc] = lds_frag(At, wm * 128 + 64 + mq * 16 + l15, kc, l4);
    if (p2) {
      stage(Bbase, &Bb[b][0], t + 2, 0);
      stage(Abase, &Ab[b][0], t + 2, 0);
    }
    __builtin_amdgcn_s_barrier();
    asm volatile("s_waitcnt lgkmcnt(0)" ::: "memory");
    __builtin_amdgcn_sched_barrier(0);
    __builtin_amdgcn_s_setprio(1);
#pragma unroll
    for (int mq = 0; mq < 4; ++mq)
#pragma unroll
      for (int n = 0; n < 2; ++n)
#pragma unroll
        for (int kc = 0; kc < 2; ++kc)
          acc[4 + mq][n] = __builtin_amdgcn_mfma_f32_16x16x32_bf16(ahi[mq][kc], bfr[n][kc], acc[4 + mq][n], 0, 0, 0);
    __builtin_amdgcn_s_setprio(0);
    if (p2) {
      asm volatile("s_waitcnt vmcnt(6)" ::: "memory");
    } else if (p1) {
      asm volatile("s_waitcnt vmcnt(2)" ::: "memory");
    }
    __builtin_amdgcn_s_barrier();
  }

  // epilogue
#pragma unroll
  for (int m = 0; m < 8; ++m) {
#pragma unroll
    for (int n = 0; n < 2; ++n) {
      int row = mt * 256 + wm * 128 + m * 16 + l4 * 4;
      int col = ct * 128 + wn * 32 + n * 16 + l15;
      float bv = bias[col];
      if constexpr (BF16OUT) {
        short4v pk4;
#pragma unroll
        for (int j = 0; j < 4; ++j) pk4[j] = f2bf(acc[m][n][j] + bv);
        if (col >= 2048) {
          int hh = (col - 2048) >> 6, dd = (col - 2048) & 63;
          int batch2 = row >> 11, tok = row & 2047;
          *(short4v*)(vTout + (((size_t)(batch2 * 16 + hh) * 64 + dd) << 11) + tok) = pk4;
        } else {
#pragma unroll
          for (int j = 0; j < 4; ++j)
            ((short*)Cout)[(size_t)(row + j) * N + col] = pk4[j];
        }
      } else {
#pragma unroll
        for (int j = 0; j < 4; ++j)
          ((float*)Cout)[(size_t)(row + j) * N + col] = acc[m][n][j] + bv;
      }
    }
  }
}

// ---------------- fused causal attention: 8 waves/block, ONE 32-row tile per wave ----------------
// Same 512 blocks and identical K/V traffic as r16 (same block -> kv range), but 8 waves per
// block: waves 0-3 own heavy tiles 63-(4bp+w), waves 4-7 own light tiles 4bp+(w-4).
// Wave concurrency doubles (4/SIMD, was 2) while the staging unit is unchanged -- the r11/r15
// mistake (duplicated staging) avoided. Per-wave serial chain halves; state halves -> fits
// the 128-VGPR cap of launch_bounds(512,4). V frags loaded AFTER the P pack (live only in PV).
__global__ __launch_bounds__(512, 4) void k_attn(const short* __restrict__ qkv,
                                                 const short* __restrict__ vT,
                                                 short* __restrict__ out) {
  constexpr int T = 2048, C3 = 3072;
  __shared__ __align__(16) short Kl[2][64 * 72];
  __shared__ __align__(16) short P_lds[8][32 * 72];
  int i_ = blockIdx.x;
  int xcd = i_ & 7, m_ = i_ >> 3;
  int bh = xcd * 8 + (m_ & 7), bp = m_ >> 3;  // bijective: all 8 bp-blocks of bh on one XCD
  int batch = bh >> 4, h = bh & 15;
  int tid = threadIdx.x, w = tid >> 6, lane = tid & 63;
  int l15 = lane & 15, l4 = lane >> 4;

  int qt = (w < 4) ? (63 - (bp * 4 + w)) : (bp * 4 + (w - 4));
  int lim = qt >> 1;
  int ktb = (63 - bp * 4) >> 1;  // block max (wave 0's lim)

  const short* kbase = qkv + (size_t)(batch * T) * C3 + 1024 + h * 64;
  const short* vbase = vT + (size_t)bh * 64 * T;

  // staging geometry: 512 threads x 1 short8 covers 64 rows x 128B
  int sr = tid >> 3, sdc = (tid & 7) * 8;

  const float SCL = 0.18033688f;
  short8 qf[2][2];  // [qc][kc]
#pragma unroll
  for (int qc = 0; qc < 2; ++qc) {
    const short* qrow = qkv + (size_t)(batch * T + qt * 32 + qc * 16 + l15) * C3 + h * 64;
#pragma unroll
    for (int kc = 0; kc < 2; ++kc) {
      short8 v = *(const short8*)(qrow + kc * 32 + l4 * 8);
#pragma unroll
      for (int i = 0; i < 8; ++i) v[i] = f2bf(bf2f(v[i]) * SCL);
      qf[qc][kc] = v;
    }
  }

  const f32x4 ZERO = f32x4{0.f, 0.f, 0.f, 0.f};
  short8 ONES;
#pragma unroll
  for (int i = 0; i < 8; ++i) ONES[i] = (short)0x3F80;  // bf16 1.0

  f32x4 o_[2][4];  // [qc][dtile]
  f32x4 lacc[2];
#pragma unroll
  for (int qc = 0; qc < 2; ++qc) {
    lacc[qc] = ZERO;
#pragma unroll
    for (int dt = 0; dt < 4; ++dt) o_[qc][dt] = ZERO;
  }

  // prologue: stage K tile 0 (reg -> padded LDS, 1 short8/thread)
  {
    short8 a = *(const short8*)(kbase + (size_t)sr * C3 + sdc);
    *(short8*)&Kl[0][sr * 72 + sdc] = a;
  }
  __syncthreads();

  short* pb = &P_lds[w][0];
  int cur = 0;
  for (int kt = 0; kt <= ktb; ++kt) {
    bool more = (kt < ktb);
    bool act = (kt <= lim);  // wave-uniform

    // prefetch next K tile to reg (block-cooperative staging: unconditional)
    short8 pre;
    if (more)
      pre = *(const short8*)(kbase + (size_t)((kt + 1) * 64 + sr) * C3 + sdc);

    if (act) {
      // K frags from LDS: A[kv_local=kvt*16+l15][k = kc*32+l4*8+e]
      const short* Kb = &Kl[cur][0];
      short8 kf[4][2];
#pragma unroll
      for (int kvt = 0; kvt < 4; ++kvt)
#pragma unroll
        for (int kc = 0; kc < 2; ++kc)
          kf[kvt][kc] = *(const short8*)(Kb + (kvt * 16 + l15) * 72 + kc * 32 + l4 * 8);

      // QK + mask + softmax + pack for this wave's tile
#pragma unroll
      for (int qc = 0; qc < 2; ++qc) {
        f32x4 s[4];
        __builtin_amdgcn_s_setprio(1);
#pragma unroll
        for (int kvt = 0; kvt < 4; ++kvt) {
          s[kvt] = __builtin_amdgcn_mfma_f32_16x16x32_bf16(kf[kvt][0], qf[qc][0], ZERO, 0, 0, 0);
          s[kvt] = __builtin_amdgcn_mfma_f32_16x16x32_bf16(kf[kvt][1], qf[qc][1], s[kvt], 0, 0, 0);
        }
        __builtin_amdgcn_s_setprio(0);

        // causal mask on the diagonal tile (verified C/D formula)
        if (kt == lim) {
          int qg = qt * 32 + qc * 16 + l15;
#pragma unroll
          for (int kvt = 0; kvt < 4; ++kvt)
#pragma unroll
            for (int j = 0; j < 4; ++j) {
              int kg = kt * 64 + kvt * 16 + l4 * 4 + j;
              if (kg > qg) s[kvt][j] = -1e30f;
            }
        }

        // fixed-max softmax: P = 2^s; pack and store to per-wave LDS
#pragma unroll
        for (int kvt = 0; kvt < 4; ++kvt) {
          float p0 = exp2f(s[kvt][0]);
          float p1 = exp2f(s[kvt][1]);
          float p2 = exp2f(s[kvt][2]);
          float p3 = exp2f(s[kvt][3]);
          unsigned lo = cvt_pk_bf16(p0, p1);
          unsigned hi = cvt_pk_bf16(p2, p3);
          *(uint2v*)(pb + (qc * 16 + l15) * 72 + kvt * 16 + l4 * 4) = uint2v{lo, hi};
        }
      }

      // V^T frags (loaded late: live only across PV, keeps VGPR under the 4-wave cap)
      short8 vf[4][2];
#pragma unroll
      for (int dt = 0; dt < 4; ++dt)
#pragma unroll
        for (int kc = 0; kc < 2; ++kc)
          vf[dt][kc] = *(const short8*)(vbase + (size_t)(dt * 16 + l15) * T + kt * 64 + kc * 32 + l4 * 8);

      // same-wave LDS write->read drain
      asm volatile("s_waitcnt lgkmcnt(0)" ::: "memory");

      // PV: O^T += V^T x P^T; l-sum via ones-MFMA
      __builtin_amdgcn_s_setprio(1);
#pragma unroll
      for (int qc = 0; qc < 2; ++qc)
#pragma unroll
        for (int kc = 0; kc < 2; ++kc) {
          short8 pf = *(const short8*)(pb + (qc * 16 + l15) * 72 + kc * 32 + l4 * 8);
          lacc[qc] = __builtin_amdgcn_mfma_f32_16x16x32_bf16(ONES, pf, lacc[qc], 0, 0, 0);
#pragma unroll
          for (int dt = 0; dt < 4; ++dt)
            o_[qc][dt] = __builtin_amdgcn_mfma_f32_16x16x32_bf16(vf[dt][kc], pf, o_[qc][dt], 0, 0, 0);
        }
      __builtin_amdgcn_s_setprio(0);
    }

    // write prefetched K into the other buffer, then the single barrier
    if (more) {
      *(short8*)&Kl[cur ^ 1][sr * 72 + sdc] = pre;
    }
    __syncthreads();
    cur ^= 1;
  }

  // epilogue: lacc[qc][j] == l for q-col l15 (all j equal) -> no shuffles
#pragma unroll
  for (int qc = 0; qc < 2; ++qc) {
    float inv = 1.f / lacc[qc][0];
    size_t rowb = (size_t)(batch * T + qt * 32 + qc * 16 + l15) * 1024 + h * 64;
#pragma unroll
    for (int dt = 0; dt < 4; ++dt) {
      short4v pk4;
#pragma unroll
      for (int j = 0; j < 4; ++j) pk4[j] = f2bf(o_[qc][dt][j] * inv);
      *(short4v*)(out + rowb + dt * 16 + l4 * 4) = pk4;
    }
  }
}

extern "C" void kernel_launch(void* const* d_in, const int* in_sizes, int n_in,
                              void* d_out, int out_size, void* d_ws, size_t ws_size,
                              hipStream_t stream) {
  const float* x      = (const float*)d_in[0];
  const float* w_attn = (const float*)d_in[1];
  const float* b_attn = (const float*)d_in[2];
  const float* w_proj = (const float*)d_in[3];
  const float* b_proj = (const float*)d_in[4];
  float* out = (float*)d_out;

  char* ws = (char*)d_ws;
  short* xb   = (short*)(ws);                    // 16,777,216 B
  short* waT  = (short*)(ws + 16777216);         //  6,291,456 B
  short* wpT  = (short*)(ws + 23068672);         //  2,097,152 B
  short* qkv  = (short*)(ws + 25165824);         // 50,331,648 B
  short* vT   = (short*)(ws + 75497472);         // 16,777,216 B  (total 92,274,688)
  short* attn = xb;                              // xb dead after gemm1

  k_convert_bf16<<<4096, 256, 0, stream>>>(x, xb, 1048576);
  k_transpose_w<<<32 * 96, 256, 0, stream>>>(w_attn, waT, 1024, 3072);
  k_transpose_w<<<32 * 32, 256, 0, stream>>>(w_proj, wpT, 1024, 1024);
  k_gemm8p<true><<<768, 512, 0, stream>>>(xb, waT, b_attn, qkv, vT, 8192, 3072, 1024);
  k_attn<<<512, 512, 0, stream>>>(qkv, vT, attn);
  k_gemm8p<false><<<256, 512, 0, stream>>>(attn, wpT, b_proj, out, nullptr, 8192, 1024, 1024);
}

// Round 20
// 225.197 us; speedup vs baseline: 1.0185x; 1.0185x over previous
//
#include <hip/hip_runtime.h>

typedef short short8 __attribute__((ext_vector_type(8)));
typedef short short4v __attribute__((ext_vector_type(4)));
typedef float f32x4 __attribute__((ext_vector_type(4)));
typedef unsigned uint2v __attribute__((ext_vector_type(2)));

__device__ __forceinline__ float bf2f(short b) {
  unsigned u = ((unsigned)(unsigned short)b) << 16;
  return __builtin_bit_cast(float, u);
}
__device__ __forceinline__ short f2bf(float f) {
  unsigned u = __builtin_bit_cast(unsigned, f);
  u += 0x7fffu + ((u >> 16) & 1u);
  return (short)(u >> 16);
}
__device__ __forceinline__ unsigned cvt_pk_bf16(float lo, float hi) {
  unsigned r;
  asm("v_cvt_pk_bf16_f32 %0, %1, %2" : "=v"(r) : "v"(lo), "v"(hi));
  return r;
}

__device__ __forceinline__ void gload_lds16(const void* g, void* l) {
  __builtin_amdgcn_global_load_lds(
      (const __attribute__((address_space(1))) unsigned int*)g,
      (__attribute__((address_space(3))) unsigned int*)l, 16, 0, 0);
}

// swizzled LDS fragment read: tile rows of 64 shorts (128B), chunk = 16B unit,
// physical chunk = logical chunk ^ (row & 7)  [T2 involution]
__device__ __forceinline__ short8 lds_frag(const short* tile, int row, int kc, int l4) {
  int chunk = (kc * 4 + l4) ^ (row & 7);
  return *(const short8*)&tile[row * 64 + chunk * 8];
}

// ---------------- fp32 -> bf16 convert (x) ----------------
__global__ __launch_bounds__(256) void k_convert_bf16(const float* __restrict__ in,
                                                      short* __restrict__ out, int n8) {
  int i = blockIdx.x * 256 + threadIdx.x;
  if (i >= n8) return;
  const float4* p = (const float4*)in;
  float4 a = p[2 * i], b = p[2 * i + 1];
  short8 o;
  o[0] = f2bf(a.x); o[1] = f2bf(a.y); o[2] = f2bf(a.z); o[3] = f2bf(a.w);
  o[4] = f2bf(b.x); o[5] = f2bf(b.y); o[6] = f2bf(b.z); o[7] = f2bf(b.w);
  ((short8*)out)[i] = o;
}

// ---------------- weight transpose+convert: w[K][N] f32 -> wT[N][K] bf16 ----------------
__global__ __launch_bounds__(256) void k_transpose_w(const float* __restrict__ w,
                                                     short* __restrict__ wT, int K, int N) {
  __shared__ float t[32][33];
  int nt = N >> 5;
  int rt = blockIdx.x / nt, ct = blockIdx.x % nt;
  int tx = threadIdx.x & 31, ty = threadIdx.x >> 5;
#pragma unroll
  for (int i = 0; i < 4; ++i) {
    int r = ty * 4 + i;
    t[r][tx] = w[(size_t)(rt * 32 + r) * N + ct * 32 + tx];
  }
  __syncthreads();
#pragma unroll
  for (int i = 0; i < 4; ++i) {
    int r = ty * 4 + i;
    wT[(size_t)(ct * 32 + r) * K + rt * 32 + tx] = f2bf(t[tx][r]);
  }
}

// ---------------- GEMM 256x128, BK=64, TWO phases/K-tile (16 MFMA each) [r18 verified] ----------------
template <bool BF16OUT>
__global__ __launch_bounds__(512, 1) void k_gemm8p(const short* __restrict__ A,
                                                   const short* __restrict__ Bt,
                                                   const float* __restrict__ bias,
                                                   void* __restrict__ Cout,
                                                   short* __restrict__ vTout,
                                                   int M, int N, int K) {
  __shared__ __align__(16) short Ab[2][256 * 64];
  __shared__ __align__(16) short Bb[2][128 * 64];
  int nt = N >> 7;
  int nwg = gridDim.x;
  int bid = blockIdx.x;
  int swz = (bid & 7) * (nwg >> 3) + (bid >> 3);  // nwg % 8 == 0 -> bijective
  int mt = swz / nt, ct = swz % nt;
  int tid = threadIdx.x, w = tid >> 6, lane = tid & 63;
  int l15 = lane & 15, l4 = lane >> 4;
  int wm = w >> 2, wn = w & 3;
  const short* Abase = A + (size_t)mt * 256 * K;
  const short* Bbase = Bt + (size_t)ct * 128 * K;
  int NT = K >> 6;

  int srow = lane >> 3;
  int slc = (lane & 7) ^ srow;

  auto stage = [&](const short* gbase, short* dstTile, int kt, int half) {
#pragma unroll
    for (int i = 0; i < 2; ++i) {
      int rowg = half * 128 + i * 64 + w * 8;
      gload_lds16(gbase + (size_t)(rowg + srow) * K + kt * 64 + slc * 8,
                  dstTile + (size_t)rowg * 64);
    }
  };

  f32x4 acc[8][2];
#pragma unroll
  for (int m = 0; m < 8; ++m)
#pragma unroll
    for (int n = 0; n < 2; ++n) acc[m][n] = f32x4{0.f, 0.f, 0.f, 0.f};

  stage(Bbase, &Bb[0][0], 0, 0);
  stage(Abase, &Ab[0][0], 0, 0);
  stage(Abase, &Ab[0][0], 0, 1);
  stage(Bbase, &Bb[1][0], 1, 0);
  stage(Abase, &Ab[1][0], 1, 0);
  asm volatile("s_waitcnt vmcnt(6)" ::: "memory");
  __builtin_amdgcn_s_barrier();

  for (int t = 0; t < NT; ++t) {
    int b = t & 1;
    const short* At = &Ab[b][0];
    const short* Btl = &Bb[b][0];
    bool p1 = (t + 1 < NT), p2 = (t + 2 < NT);

    short8 alo[4][2], ahi[4][2], bfr[2][2];

    // ===== phase 1: m-lo x n (B cached for ph2); stage A-hi(t+1) =====
#pragma unroll
    for (int mq = 0; mq < 4; ++mq)
#pragma unroll
      for (int kc = 0; kc < 2; ++kc)
        alo[mq][kc] = lds_frag(At, wm * 128 + mq * 16 + l15, kc, l4);
#pragma unroll
    for (int n = 0; n < 2; ++n)
#pragma unroll
      for (int kc = 0; kc < 2; ++kc)
        bfr[n][kc] = lds_frag(Btl, wn * 32 + n * 16 + l15, kc, l4);
    if (p1) stage(Abase, &Ab[(t + 1) & 1][0], t + 1, 1);
    __builtin_amdgcn_s_barrier();
    asm volatile("s_waitcnt lgkmcnt(0)" ::: "memory");
    __builtin_amdgcn_sched_barrier(0);
    __builtin_amdgcn_s_setprio(1);
#pragma unroll
    for (int mq = 0; mq < 4; ++mq)
#pragma unroll
      for (int n = 0; n < 2; ++n)
#pragma unroll
        for (int kc = 0; kc < 2; ++kc)
          acc[mq][n] = __builtin_amdgcn_mfma_f32_16x16x32_bf16(alo[mq][kc], bfr[n][kc], acc[mq][n], 0, 0, 0);
    __builtin_amdgcn_s_setprio(0);
    if (p1) {
      asm volatile("s_waitcnt vmcnt(6)" ::: "memory");
    } else {
      asm volatile("s_waitcnt vmcnt(0)" ::: "memory");
    }
    __builtin_amdgcn_s_barrier();

    // ===== phase 2: m-hi x n (B from regs); stage B(t+2) + A-lo(t+2) =====
#pragma unroll
    for (int mq = 0; mq < 4; ++mq)
#pragma unroll
      for (int kc = 0; kc < 2; ++kc)
        ahi[mq][kc] = lds_frag(At, wm * 128 + 64 + mq * 16 + l15, kc, l4);
    if (p2) {
      stage(Bbase, &Bb[b][0], t + 2, 0);
      stage(Abase, &Ab[b][0], t + 2, 0);
    }
    __builtin_amdgcn_s_barrier();
    asm volatile("s_waitcnt lgkmcnt(0)" ::: "memory");
    __builtin_amdgcn_sched_barrier(0);
    __builtin_amdgcn_s_setprio(1);
#pragma unroll
    for (int mq = 0; mq < 4; ++mq)
#pragma unroll
      for (int n = 0; n < 2; ++n)
#pragma unroll
        for (int kc = 0; kc < 2; ++kc)
          acc[4 + mq][n] = __builtin_amdgcn_mfma_f32_16x16x32_bf16(ahi[mq][kc], bfr[n][kc], acc[4 + mq][n], 0, 0, 0);
    __builtin_amdgcn_s_setprio(0);
    if (p2) {
      asm volatile("s_waitcnt vmcnt(6)" ::: "memory");
    } else if (p1) {
      asm volatile("s_waitcnt vmcnt(2)" ::: "memory");
    }
    __builtin_amdgcn_s_barrier();
  }

  // epilogue
#pragma unroll
  for (int m = 0; m < 8; ++m) {
#pragma unroll
    for (int n = 0; n < 2; ++n) {
      int row = mt * 256 + wm * 128 + m * 16 + l4 * 4;
      int col = ct * 128 + wn * 32 + n * 16 + l15;
      float bv = bias[col];
      if constexpr (BF16OUT) {
        short4v pk4;
#pragma unroll
        for (int j = 0; j < 4; ++j) pk4[j] = f2bf(acc[m][n][j] + bv);
        if (col >= 2048) {
          int hh = (col - 2048) >> 6, dd = (col - 2048) & 63;
          int batch2 = row >> 11, tok = row & 2047;
          *(short4v*)(vTout + (((size_t)(batch2 * 16 + hh) * 64 + dd) << 11) + tok) = pk4;
        } else {
#pragma unroll
          for (int j = 0; j < 4; ++j)
            ((short*)Cout)[(size_t)(row + j) * N + col] = pk4[j];
        }
      } else {
#pragma unroll
        for (int j = 0; j < 4; ++j)
          ((float*)Cout)[(size_t)(row + j) * N + col] = acc[m][n][j] + bv;
      }
    }
  }
}

// ---------------- fused causal attention: 8 waves/block, ONE 32-row tile per wave ----------------
// r19 structure with launch_bounds(512,2): r19's regression was the (512,4) hint forcing the
// compiler to a 64-VGPR budget (massive scratch spill, WRITE_SIZE 30MB). With the cap at 256
// the natural allocation (~100-125) fits the 128-VGPR threshold for 16 waves/CU, so the HW
// grants 2 blocks/CU x 8 waves = 4 waves/SIMD -- the concurrency r19 proved reachable
// (occupancy 38%) without the spill. All else identical to r19.
__global__ __launch_bounds__(512, 2) void k_attn(const short* __restrict__ qkv,
                                                 const short* __restrict__ vT,
                                                 short* __restrict__ out) {
  constexpr int T = 2048, C3 = 3072;
  __shared__ __align__(16) short Kl[2][64 * 72];
  __shared__ __align__(16) short P_lds[8][32 * 72];
  int i_ = blockIdx.x;
  int xcd = i_ & 7, m_ = i_ >> 3;
  int bh = xcd * 8 + (m_ & 7), bp = m_ >> 3;  // bijective: all 8 bp-blocks of bh on one XCD
  int batch = bh >> 4, h = bh & 15;
  int tid = threadIdx.x, w = tid >> 6, lane = tid & 63;
  int l15 = lane & 15, l4 = lane >> 4;

  int qt = (w < 4) ? (63 - (bp * 4 + w)) : (bp * 4 + (w - 4));
  int lim = qt >> 1;
  int ktb = (63 - bp * 4) >> 1;  // block max (wave 0's lim)

  const short* kbase = qkv + (size_t)(batch * T) * C3 + 1024 + h * 64;
  const short* vbase = vT + (size_t)bh * 64 * T;

  // staging geometry: 512 threads x 1 short8 covers 64 rows x 128B
  int sr = tid >> 3, sdc = (tid & 7) * 8;

  const float SCL = 0.18033688f;
  short8 qf[2][2];  // [qc][kc]
#pragma unroll
  for (int qc = 0; qc < 2; ++qc) {
    const short* qrow = qkv + (size_t)(batch * T + qt * 32 + qc * 16 + l15) * C3 + h * 64;
#pragma unroll
    for (int kc = 0; kc < 2; ++kc) {
      short8 v = *(const short8*)(qrow + kc * 32 + l4 * 8);
#pragma unroll
      for (int i = 0; i < 8; ++i) v[i] = f2bf(bf2f(v[i]) * SCL);
      qf[qc][kc] = v;
    }
  }

  const f32x4 ZERO = f32x4{0.f, 0.f, 0.f, 0.f};
  short8 ONES;
#pragma unroll
  for (int i = 0; i < 8; ++i) ONES[i] = (short)0x3F80;  // bf16 1.0

  f32x4 o_[2][4];  // [qc][dtile]
  f32x4 lacc[2];
#pragma unroll
  for (int qc = 0; qc < 2; ++qc) {
    lacc[qc] = ZERO;
#pragma unroll
    for (int dt = 0; dt < 4; ++dt) o_[qc][dt] = ZERO;
  }

  // prologue: stage K tile 0 (reg -> padded LDS, 1 short8/thread)
  {
    short8 a = *(const short8*)(kbase + (size_t)sr * C3 + sdc);
    *(short8*)&Kl[0][sr * 72 + sdc] = a;
  }
  __syncthreads();

  short* pb = &P_lds[w][0];
  int cur = 0;
  for (int kt = 0; kt <= ktb; ++kt) {
    bool more = (kt < ktb);
    bool act = (kt <= lim);  // wave-uniform

    // prefetch next K tile to reg (block-cooperative staging: unconditional)
    short8 pre;
    if (more)
      pre = *(const short8*)(kbase + (size_t)((kt + 1) * 64 + sr) * C3 + sdc);

    if (act) {
      // K frags from LDS: A[kv_local=kvt*16+l15][k = kc*32+l4*8+e]
      const short* Kb = &Kl[cur][0];
      short8 kf[4][2];
#pragma unroll
      for (int kvt = 0; kvt < 4; ++kvt)
#pragma unroll
        for (int kc = 0; kc < 2; ++kc)
          kf[kvt][kc] = *(const short8*)(Kb + (kvt * 16 + l15) * 72 + kc * 32 + l4 * 8);

      // QK + mask + softmax + pack for this wave's tile
#pragma unroll
      for (int qc = 0; qc < 2; ++qc) {
        f32x4 s[4];
        __builtin_amdgcn_s_setprio(1);
#pragma unroll
        for (int kvt = 0; kvt < 4; ++kvt) {
          s[kvt] = __builtin_amdgcn_mfma_f32_16x16x32_bf16(kf[kvt][0], qf[qc][0], ZERO, 0, 0, 0);
          s[kvt] = __builtin_amdgcn_mfma_f32_16x16x32_bf16(kf[kvt][1], qf[qc][1], s[kvt], 0, 0, 0);
        }
        __builtin_amdgcn_s_setprio(0);

        // causal mask on the diagonal tile (verified C/D formula)
        if (kt == lim) {
          int qg = qt * 32 + qc * 16 + l15;
#pragma unroll
          for (int kvt = 0; kvt < 4; ++kvt)
#pragma unroll
            for (int j = 0; j < 4; ++j) {
              int kg = kt * 64 + kvt * 16 + l4 * 4 + j;
              if (kg > qg) s[kvt][j] = -1e30f;
            }
        }

        // fixed-max softmax: P = 2^s; pack and store to per-wave LDS
#pragma unroll
        for (int kvt = 0; kvt < 4; ++kvt) {
          float p0 = exp2f(s[kvt][0]);
          float p1 = exp2f(s[kvt][1]);
          float p2 = exp2f(s[kvt][2]);
          float p3 = exp2f(s[kvt][3]);
          unsigned lo = cvt_pk_bf16(p0, p1);
          unsigned hi = cvt_pk_bf16(p2, p3);
          *(uint2v*)(pb + (qc * 16 + l15) * 72 + kvt * 16 + l4 * 4) = uint2v{lo, hi};
        }
      }

      // V^T frags (loaded late: live only across PV)
      short8 vf[4][2];
#pragma unroll
      for (int dt = 0; dt < 4; ++dt)
#pragma unroll
        for (int kc = 0; kc < 2; ++kc)
          vf[dt][kc] = *(const short8*)(vbase + (size_t)(dt * 16 + l15) * T + kt * 64 + kc * 32 + l4 * 8);

      // same-wave LDS write->read drain
      asm volatile("s_waitcnt lgkmcnt(0)" ::: "memory");

      // PV: O^T += V^T x P^T; l-sum via ones-MFMA
      __builtin_amdgcn_s_setprio(1);
#pragma unroll
      for (int qc = 0; qc < 2; ++qc)
#pragma unroll
        for (int kc = 0; kc < 2; ++kc) {
          short8 pf = *(const short8*)(pb + (qc * 16 + l15) * 72 + kc * 32 + l4 * 8);
          lacc[qc] = __builtin_amdgcn_mfma_f32_16x16x32_bf16(ONES, pf, lacc[qc], 0, 0, 0);
#pragma unroll
          for (int dt = 0; dt < 4; ++dt)
            o_[qc][dt] = __builtin_amdgcn_mfma_f32_16x16x32_bf16(vf[dt][kc], pf, o_[qc][dt], 0, 0, 0);
        }
      __builtin_amdgcn_s_setprio(0);
    }

    // write prefetched K into the other buffer, then the single barrier
    if (more) {
      *(short8*)&Kl[cur ^ 1][sr * 72 + sdc] = pre;
    }
    __syncthreads();
    cur ^= 1;
  }

  // epilogue: lacc[qc][j] == l for q-col l15 (all j equal) -> no shuffles
#pragma unroll
  for (int qc = 0; qc < 2; ++qc) {
    float inv = 1.f / lacc[qc][0];
    size_t rowb = (size_t)(batch * T + qt * 32 + qc * 16 + l15) * 1024 + h * 64;
#pragma unroll
    for (int dt = 0; dt < 4; ++dt) {
      short4v pk4;
#pragma unroll
      for (int j = 0; j < 4; ++j) pk4[j] = f2bf(o_[qc][dt][j] * inv);
      *(short4v*)(out + rowb + dt * 16 + l4 * 4) = pk4;
    }
  }
}

extern "C" void kernel_launch(void* const* d_in, const int* in_sizes, int n_in,
                              void* d_out, int out_size, void* d_ws, size_t ws_size,
                              hipStream_t stream) {
  const float* x      = (const float*)d_in[0];
  const float* w_attn = (const float*)d_in[1];
  const float* b_attn = (const float*)d_in[2];
  const float* w_proj = (const float*)d_in[3];
  const float* b_proj = (const float*)d_in[4];
  float* out = (float*)d_out;

  char* ws = (char*)d_ws;
  short* xb   = (short*)(ws);                    // 16,777,216 B
  short* waT  = (short*)(ws + 16777216);         //  6,291,456 B
  short* wpT  = (short*)(ws + 23068672);         //  2,097,152 B
  short* qkv  = (short*)(ws + 25165824);         // 50,331,648 B
  short* vT   = (short*)(ws + 75497472);         // 16,777,216 B  (total 92,274,688)
  short* attn = xb;                              // xb dead after gemm1

  k_convert_bf16<<<4096, 256, 0, stream>>>(x, xb, 1048576);
  k_transpose_w<<<32 * 96, 256, 0, stream>>>(w_attn, waT, 1024, 3072);
  k_transpose_w<<<32 * 32, 256, 0, stream>>>(w_proj, wpT, 1024, 1024);
  k_gemm8p<true><<<768, 512, 0, stream>>>(xb, waT, b_attn, qkv, vT, 8192, 3072, 1024);
  k_attn<<<512, 512, 0, stream>>>(qkv, vT, attn);
  k_gemm8p<false><<<256, 512, 0, stream>>>(attn, wpT, b_proj, out, nullptr, 8192, 1024, 1024);
}

// Round 21
// 190.944 us; speedup vs baseline: 1.2012x; 1.1794x over previous
//
#include <hip/hip_runtime.h>

typedef short short8 __attribute__((ext_vector_type(8)));
typedef short short4v __attribute__((ext_vector_type(4)));
typedef float f32x4 __attribute__((ext_vector_type(4)));
typedef unsigned uint2v __attribute__((ext_vector_type(2)));

__device__ __forceinline__ float bf2f(short b) {
  unsigned u = ((unsigned)(unsigned short)b) << 16;
  return __builtin_bit_cast(float, u);
}
__device__ __forceinline__ short f2bf(float f) {
  unsigned u = __builtin_bit_cast(unsigned, f);
  u += 0x7fffu + ((u >> 16) & 1u);
  return (short)(u >> 16);
}
__device__ __forceinline__ unsigned cvt_pk_bf16(float lo, float hi) {
  unsigned r;
  asm("v_cvt_pk_bf16_f32 %0, %1, %2" : "=v"(r) : "v"(lo), "v"(hi));
  return r;
}

__device__ __forceinline__ void gload_lds16(const void* g, void* l) {
  __builtin_amdgcn_global_load_lds(
      (const __attribute__((address_space(1))) unsigned int*)g,
      (__attribute__((address_space(3))) unsigned int*)l, 16, 0, 0);
}

// swizzled LDS fragment read: tile rows of 64 shorts (128B), chunk = 16B unit,
// physical chunk = logical chunk ^ (row & 7)  [T2 involution]
__device__ __forceinline__ short8 lds_frag(const short* tile, int row, int kc, int l4) {
  int chunk = (kc * 4 + l4) ^ (row & 7);
  return *(const short8*)&tile[row * 64 + chunk * 8];
}

// ---------------- fp32 -> bf16 convert (x) ----------------
__global__ __launch_bounds__(256) void k_convert_bf16(const float* __restrict__ in,
                                                      short* __restrict__ out, int n8) {
  int i = blockIdx.x * 256 + threadIdx.x;
  if (i >= n8) return;
  const float4* p = (const float4*)in;
  float4 a = p[2 * i], b = p[2 * i + 1];
  short8 o;
  o[0] = f2bf(a.x); o[1] = f2bf(a.y); o[2] = f2bf(a.z); o[3] = f2bf(a.w);
  o[4] = f2bf(b.x); o[5] = f2bf(b.y); o[6] = f2bf(b.z); o[7] = f2bf(b.w);
  ((short8*)out)[i] = o;
}

// ---------------- weight transpose+convert: w[K][N] f32 -> wT[N][K] bf16 ----------------
__global__ __launch_bounds__(256) void k_transpose_w(const float* __restrict__ w,
                                                     short* __restrict__ wT, int K, int N) {
  __shared__ float t[32][33];
  int nt = N >> 5;
  int rt = blockIdx.x / nt, ct = blockIdx.x % nt;
  int tx = threadIdx.x & 31, ty = threadIdx.x >> 5;
#pragma unroll
  for (int i = 0; i < 4; ++i) {
    int r = ty * 4 + i;
    t[r][tx] = w[(size_t)(rt * 32 + r) * N + ct * 32 + tx];
  }
  __syncthreads();
#pragma unroll
  for (int i = 0; i < 4; ++i) {
    int r = ty * 4 + i;
    wT[(size_t)(ct * 32 + r) * K + rt * 32 + tx] = f2bf(t[tx][r]);
  }
}

// ---------------- GEMM 256x256, BK=64, TWO phases/K-tile (32 MFMA each) ----------------
// Widened-N version of the r18-verified 2-phase skeleton: B quadrant frags (4x2 short8)
// cached in regs ph1->ph2, so B's LDS reads end at ph1; A-lo reads end ph1; A-hi reads end
// ph2. Staging (in-place, 2 buffers): A-hi(t+1)@ph1 -> buf b^1 (last reader ph2(t-1));
// B(t+2)+A-lo(t+2)@ph2 -> buf b (last readers ph1(t)). 8 loads/tile/wave -> steady vmcnt(8)
// at both phase ends (FIFO-audited incl. prologue), tails 0/2. LDS 128KB, ~215 VGPR,
// 8 waves = 2 waves/SIMD at 1 block/CU. Grid 384 (%8==0 -> bijective XCD swizzle).
// BF16OUT: cols >= 2048 (V part of qkv) written transposed into vT[bh][d][tok].
template <bool BF16OUT>
__global__ __launch_bounds__(512, 1) void k_gemm2ph256(const short* __restrict__ A,
                                                       const short* __restrict__ Bt,
                                                       const float* __restrict__ bias,
                                                       void* __restrict__ Cout,
                                                       short* __restrict__ vTout,
                                                       int M, int N, int K) {
  __shared__ __align__(16) short Ab[2][256 * 64];
  __shared__ __align__(16) short Bb[2][256 * 64];
  int nt = N >> 8;
  int nwg = gridDim.x;
  int bid = blockIdx.x;
  int swz = (bid & 7) * (nwg >> 3) + (bid >> 3);
  int mt = swz / nt, ct = swz % nt;
  int tid = threadIdx.x, w = tid >> 6, lane = tid & 63;
  int l15 = lane & 15, l4 = lane >> 4;
  int wm = w >> 2, wn = w & 3;
  const short* Abase = A + (size_t)mt * 256 * K;
  const short* Bbase = Bt + (size_t)ct * 256 * K;
  int NT = K >> 6;

  int srow = lane >> 3;
  int slc = (lane & 7) ^ srow;

  // stage one 128-row half: linear LDS dest, XOR-swizzled global source (2 issues/wave)
  auto stage = [&](const short* gbase, short* dstTile, int kt, int half) {
#pragma unroll
    for (int i = 0; i < 2; ++i) {
      int rowg = half * 128 + i * 64 + w * 8;
      gload_lds16(gbase + (size_t)(rowg + srow) * K + kt * 64 + slc * 8,
                  dstTile + (size_t)rowg * 64);
    }
  };

  f32x4 acc[8][4];
#pragma unroll
  for (int m = 0; m < 8; ++m)
#pragma unroll
    for (int n = 0; n < 4; ++n) acc[m][n] = f32x4{0.f, 0.f, 0.f, 0.f};

  // prologue: B0(4), A0(4), B1(4), A-lo1(2) = 14 loads; wait tile0 (tile1's 6 in flight)
  stage(Bbase, &Bb[0][0], 0, 0);
  stage(Bbase, &Bb[0][0], 0, 1);
  stage(Abase, &Ab[0][0], 0, 0);
  stage(Abase, &Ab[0][0], 0, 1);
  stage(Bbase, &Bb[1][0], 1, 0);
  stage(Bbase, &Bb[1][0], 1, 1);
  stage(Abase, &Ab[1][0], 1, 0);
  asm volatile("s_waitcnt vmcnt(6)" ::: "memory");
  __builtin_amdgcn_s_barrier();

  for (int t = 0; t < NT; ++t) {
    int b = t & 1;
    const short* At = &Ab[b][0];
    const short* Btl = &Bb[b][0];
    bool p1 = (t + 1 < NT), p2 = (t + 2 < NT);

    short8 alo[4][2], ahi[4][2], bfr[4][2];

    // ===== phase 1: m-lo x all n (B cached for ph2); stage A-hi(t+1) =====
#pragma unroll
    for (int mq = 0; mq < 4; ++mq)
#pragma unroll
      for (int kc = 0; kc < 2; ++kc)
        alo[mq][kc] = lds_frag(At, wm * 128 + mq * 16 + l15, kc, l4);
#pragma unroll
    for (int nq = 0; nq < 4; ++nq)
#pragma unroll
      for (int kc = 0; kc < 2; ++kc)
        bfr[nq][kc] = lds_frag(Btl, wn * 64 + nq * 16 + l15, kc, l4);
    if (p1) stage(Abase, &Ab[(t + 1) & 1][0], t + 1, 1);  // A-hi(t+1): last reader ph2(t-1)
    __builtin_amdgcn_s_barrier();
    asm volatile("s_waitcnt lgkmcnt(0)" ::: "memory");
    __builtin_amdgcn_sched_barrier(0);
    __builtin_amdgcn_s_setprio(1);
#pragma unroll
    for (int mq = 0; mq < 4; ++mq)
#pragma unroll
      for (int nq = 0; nq < 4; ++nq)
#pragma unroll
        for (int kc = 0; kc < 2; ++kc)
          acc[mq][nq] = __builtin_amdgcn_mfma_f32_16x16x32_bf16(alo[mq][kc], bfr[nq][kc], acc[mq][nq], 0, 0, 0);
    __builtin_amdgcn_s_setprio(0);
    // A-hi(t) (issued ph1(t-1)) must land before ph2's ds_reads; 8 newer in flight if p1
    if (p1) {
      asm volatile("s_waitcnt vmcnt(8)" ::: "memory");
    } else {
      asm volatile("s_waitcnt vmcnt(0)" ::: "memory");
    }
    __builtin_amdgcn_s_barrier();  // ph1-end: all B + A-lo reads of tile t complete

    // ===== phase 2: m-hi x all n (B from regs); stage B(t+2) + A-lo(t+2) =====
#pragma unroll
    for (int mq = 0; mq < 4; ++mq)
#pragma unroll
      for (int kc = 0; kc < 2; ++kc)
        ahi[mq][kc] = lds_frag(At, wm * 128 + 64 + mq * 16 + l15, kc, l4);
    if (p2) {
      stage(Bbase, &Bb[b][0], t + 2, 0);
      stage(Bbase, &Bb[b][0], t + 2, 1);
      stage(Abase, &Ab[b][0], t + 2, 0);
    }
    __builtin_amdgcn_s_barrier();
    asm volatile("s_waitcnt lgkmcnt(0)" ::: "memory");
    __builtin_amdgcn_sched_barrier(0);
    __builtin_amdgcn_s_setprio(1);
#pragma unroll
    for (int mq = 0; mq < 4; ++mq)
#pragma unroll
      for (int nq = 0; nq < 4; ++nq)
#pragma unroll
        for (int kc = 0; kc < 2; ++kc)
          acc[4 + mq][nq] = __builtin_amdgcn_mfma_f32_16x16x32_bf16(ahi[mq][kc], bfr[nq][kc], acc[4 + mq][nq], 0, 0, 0);
    __builtin_amdgcn_s_setprio(0);
    // B(t+1)+A-lo(t+1) (issued ph2(t-1)) must land before ph1(t+1)'s ds_reads
    if (p2) {
      asm volatile("s_waitcnt vmcnt(8)" ::: "memory");
    } else if (p1) {
      asm volatile("s_waitcnt vmcnt(2)" ::: "memory");
    }
    __builtin_amdgcn_s_barrier();  // ph2-end: all A-hi reads of tile t complete
  }

  // epilogue
#pragma unroll
  for (int m = 0; m < 8; ++m) {
#pragma unroll
    for (int n = 0; n < 4; ++n) {
      int row = mt * 256 + wm * 128 + m * 16 + l4 * 4;
      int col = ct * 256 + wn * 64 + n * 16 + l15;
      float bv = bias[col];
      if constexpr (BF16OUT) {
        short4v pk4;
#pragma unroll
        for (int j = 0; j < 4; ++j) pk4[j] = f2bf(acc[m][n][j] + bv);
        if (col >= 2048) {
          int hh = (col - 2048) >> 6, dd = (col - 2048) & 63;
          int batch2 = row >> 11, tok = row & 2047;
          *(short4v*)(vTout + (((size_t)(batch2 * 16 + hh) * 64 + dd) << 11) + tok) = pk4;
        } else {
#pragma unroll
          for (int j = 0; j < 4; ++j)
            ((short*)Cout)[(size_t)(row + j) * N + col] = pk4[j];
        }
      } else {
#pragma unroll
        for (int j = 0; j < 4; ++j)
          ((float*)Cout)[(size_t)(row + j) * N + col] = acc[m][n][j] + bv;
      }
    }
  }
}

// ---------------- GEMM 256x128, BK=64, TWO phases/K-tile (16 MFMA each) [r18 verified] ----------------
template <bool BF16OUT>
__global__ __launch_bounds__(512, 1) void k_gemm8p(const short* __restrict__ A,
                                                   const short* __restrict__ Bt,
                                                   const float* __restrict__ bias,
                                                   void* __restrict__ Cout,
                                                   short* __restrict__ vTout,
                                                   int M, int N, int K) {
  __shared__ __align__(16) short Ab[2][256 * 64];
  __shared__ __align__(16) short Bb[2][128 * 64];
  int nt = N >> 7;
  int nwg = gridDim.x;
  int bid = blockIdx.x;
  int swz = (bid & 7) * (nwg >> 3) + (bid >> 3);
  int mt = swz / nt, ct = swz % nt;
  int tid = threadIdx.x, w = tid >> 6, lane = tid & 63;
  int l15 = lane & 15, l4 = lane >> 4;
  int wm = w >> 2, wn = w & 3;
  const short* Abase = A + (size_t)mt * 256 * K;
  const short* Bbase = Bt + (size_t)ct * 128 * K;
  int NT = K >> 6;

  int srow = lane >> 3;
  int slc = (lane & 7) ^ srow;

  auto stage = [&](const short* gbase, short* dstTile, int kt, int half) {
#pragma unroll
    for (int i = 0; i < 2; ++i) {
      int rowg = half * 128 + i * 64 + w * 8;
      gload_lds16(gbase + (size_t)(rowg + srow) * K + kt * 64 + slc * 8,
                  dstTile + (size_t)rowg * 64);
    }
  };

  f32x4 acc[8][2];
#pragma unroll
  for (int m = 0; m < 8; ++m)
#pragma unroll
    for (int n = 0; n < 2; ++n) acc[m][n] = f32x4{0.f, 0.f, 0.f, 0.f};

  stage(Bbase, &Bb[0][0], 0, 0);
  stage(Abase, &Ab[0][0], 0, 0);
  stage(Abase, &Ab[0][0], 0, 1);
  stage(Bbase, &Bb[1][0], 1, 0);
  stage(Abase, &Ab[1][0], 1, 0);
  asm volatile("s_waitcnt vmcnt(6)" ::: "memory");
  __builtin_amdgcn_s_barrier();

  for (int t = 0; t < NT; ++t) {
    int b = t & 1;
    const short* At = &Ab[b][0];
    const short* Btl = &Bb[b][0];
    bool p1 = (t + 1 < NT), p2 = (t + 2 < NT);

    short8 alo[4][2], ahi[4][2], bfr[2][2];

#pragma unroll
    for (int mq = 0; mq < 4; ++mq)
#pragma unroll
      for (int kc = 0; kc < 2; ++kc)
        alo[mq][kc] = lds_frag(At, wm * 128 + mq * 16 + l15, kc, l4);
#pragma unroll
    for (int n = 0; n < 2; ++n)
#pragma unroll
      for (int kc = 0; kc < 2; ++kc)
        bfr[n][kc] = lds_frag(Btl, wn * 32 + n * 16 + l15, kc, l4);
    if (p1) stage(Abase, &Ab[(t + 1) & 1][0], t + 1, 1);
    __builtin_amdgcn_s_barrier();
    asm volatile("s_waitcnt lgkmcnt(0)" ::: "memory");
    __builtin_amdgcn_sched_barrier(0);
    __builtin_amdgcn_s_setprio(1);
#pragma unroll
    for (int mq = 0; mq < 4; ++mq)
#pragma unroll
      for (int n = 0; n < 2; ++n)
#pragma unroll
        for (int kc = 0; kc < 2; ++kc)
          acc[mq][n] = __builtin_amdgcn_mfma_f32_16x16x32_bf16(alo[mq][kc], bfr[n][kc], acc[mq][n], 0, 0, 0);
    __builtin_amdgcn_s_setprio(0);
    if (p1) {
      asm volatile("s_waitcnt vmcnt(6)" ::: "memory");
    } else {
      asm volatile("s_waitcnt vmcnt(0)" ::: "memory");
    }
    __builtin_amdgcn_s_barrier();

#pragma unroll
    for (int mq = 0; mq < 4; ++mq)
#pragma unroll
      for (int kc = 0; kc < 2; ++kc)
        ahi[mq][kc] = lds_frag(At, wm * 128 + 64 + mq * 16 + l15, kc, l4);
    if (p2) {
      stage(Bbase, &Bb[b][0], t + 2, 0);
      stage(Abase, &Ab[b][0], t + 2, 0);
    }
    __builtin_amdgcn_s_barrier();
    asm volatile("s_waitcnt lgkmcnt(0)" ::: "memory");
    __builtin_amdgcn_sched_barrier(0);
    __builtin_amdgcn_s_setprio(1);
#pragma unroll
    for (int mq = 0; mq < 4; ++mq)
#pragma unroll
      for (int n = 0; n < 2; ++n)
#pragma unroll
        for (int kc = 0; kc < 2; ++kc)
          acc[4 + mq][n] = __builtin_amdgcn_mfma_f32_16x16x32_bf16(ahi[mq][kc], bfr[n][kc], acc[4 + mq][n], 0, 0, 0);
    __builtin_amdgcn_s_setprio(0);
    if (p2) {
      asm volatile("s_waitcnt vmcnt(6)" ::: "memory");
    } else if (p1) {
      asm volatile("s_waitcnt vmcnt(2)" ::: "memory");
    }
    __builtin_amdgcn_s_barrier();
  }

#pragma unroll
  for (int m = 0; m < 8; ++m) {
#pragma unroll
    for (int n = 0; n < 2; ++n) {
      int row = mt * 256 + wm * 128 + m * 16 + l4 * 4;
      int col = ct * 128 + wn * 32 + n * 16 + l15;
      float bv = bias[col];
      if constexpr (BF16OUT) {
        short4v pk4;
#pragma unroll
        for (int j = 0; j < 4; ++j) pk4[j] = f2bf(acc[m][n][j] + bv);
        if (col >= 2048) {
          int hh = (col - 2048) >> 6, dd = (col - 2048) & 63;
          int batch2 = row >> 11, tok = row & 2047;
          *(short4v*)(vTout + (((size_t)(batch2 * 16 + hh) * 64 + dd) << 11) + tok) = pk4;
        } else {
#pragma unroll
          for (int j = 0; j < 4; ++j)
            ((short*)Cout)[(size_t)(row + j) * N + col] = pk4[j];
        }
      } else {
#pragma unroll
        for (int j = 0; j < 4; ++j)
          ((float*)Cout)[(size_t)(row + j) * N + col] = acc[m][n][j] + bv;
      }
    }
  }
}

// ---------------- fused causal attention (r16/r18 structure, verified 83us) ----------------
__global__ __launch_bounds__(256, 2) void k_attn(const short* __restrict__ qkv,
                                                 const short* __restrict__ vT,
                                                 short* __restrict__ out) {
  constexpr int T = 2048, C3 = 3072;
  __shared__ __align__(16) short Kl[2][64 * 72];
  __shared__ __align__(16) short P_lds[4][2][32 * 72];
  int i_ = blockIdx.x;
  int xcd = i_ & 7, m_ = i_ >> 3;
  int bh = xcd * 8 + (m_ & 7), bp = m_ >> 3;
  int batch = bh >> 4, h = bh & 15;
  int tid = threadIdx.x, w = tid >> 6, lane = tid & 63;
  int l15 = lane & 15, l4 = lane >> 4;

  int qt[2];
  qt[0] = 63 - (bp * 4 + w);
  qt[1] = bp * 4 + w;
  int lim[2] = {qt[0] >> 1, qt[1] >> 1};
  int ktb = (63 - bp * 4) >> 1;

  const short* kbase = qkv + (size_t)(batch * T) * C3 + 1024 + h * 64;
  const short* vbase = vT + (size_t)bh * 64 * T;

  int sr0 = tid >> 3, sr1 = 32 + (tid >> 3), sdc = (tid & 7) * 8;

  const float SCL = 0.18033688f;
  short8 qf[2][2][2];
#pragma unroll
  for (int t = 0; t < 2; ++t)
#pragma unroll
    for (int qc = 0; qc < 2; ++qc) {
      const short* qrow = qkv + (size_t)(batch * T + qt[t] * 32 + qc * 16 + l15) * C3 + h * 64;
#pragma unroll
      for (int kc = 0; kc < 2; ++kc) {
        short8 v = *(const short8*)(qrow + kc * 32 + l4 * 8);
#pragma unroll
        for (int i = 0; i < 8; ++i) v[i] = f2bf(bf2f(v[i]) * SCL);
        qf[t][qc][kc] = v;
      }
    }

  const f32x4 ZERO = f32x4{0.f, 0.f, 0.f, 0.f};
  short8 ONES;
#pragma unroll
  for (int i = 0; i < 8; ++i) ONES[i] = (short)0x3F80;  // bf16 1.0

  f32x4 o_[2][2][4];
  f32x4 lacc[2][2];
#pragma unroll
  for (int t = 0; t < 2; ++t)
#pragma unroll
    for (int qc = 0; qc < 2; ++qc) {
      lacc[t][qc] = ZERO;
#pragma unroll
      for (int dt = 0; dt < 4; ++dt) o_[t][qc][dt] = ZERO;
    }

  {
    short8 a = *(const short8*)(kbase + (size_t)sr0 * C3 + sdc);
    short8 b = *(const short8*)(kbase + (size_t)sr1 * C3 + sdc);
    *(short8*)&Kl[0][sr0 * 72 + sdc] = a;
    *(short8*)&Kl[0][sr1 * 72 + sdc] = b;
  }
  __syncthreads();

  int cur = 0;
  for (int kt = 0; kt <= ktb; ++kt) {
    bool more = (kt < ktb);
    bool act0 = (kt <= lim[0]), act1 = (kt <= lim[1]);

    short8 pre0, pre1;
    if (more) {
      pre0 = *(const short8*)(kbase + (size_t)((kt + 1) * 64 + sr0) * C3 + sdc);
      pre1 = *(const short8*)(kbase + (size_t)((kt + 1) * 64 + sr1) * C3 + sdc);
    }

    const short* Kb = &Kl[cur][0];
    short8 kf[4][2];
#pragma unroll
    for (int kvt = 0; kvt < 4; ++kvt)
#pragma unroll
      for (int kc = 0; kc < 2; ++kc)
        kf[kvt][kc] = *(const short8*)(Kb + (kvt * 16 + l15) * 72 + kc * 32 + l4 * 8);

    short8 vf[4][2];
#pragma unroll
    for (int dt = 0; dt < 4; ++dt)
#pragma unroll
      for (int kc = 0; kc < 2; ++kc)
        vf[dt][kc] = *(const short8*)(vbase + (size_t)(dt * 16 + l15) * T + kt * 64 + kc * 32 + l4 * 8);

    // phase A: QK + mask + softmax + pack for BOTH tiles (independent chains)
#pragma unroll
    for (int t = 0; t < 2; ++t) {
      bool act = (t == 0) ? act0 : act1;
      if (!act) continue;
      short* pb = &P_lds[w][t][0];

#pragma unroll
      for (int qc = 0; qc < 2; ++qc) {
        f32x4 s[4];
        __builtin_amdgcn_s_setprio(1);
#pragma unroll
        for (int kvt = 0; kvt < 4; ++kvt) {
          s[kvt] = __builtin_amdgcn_mfma_f32_16x16x32_bf16(kf[kvt][0], qf[t][qc][0], ZERO, 0, 0, 0);
          s[kvt] = __builtin_amdgcn_mfma_f32_16x16x32_bf16(kf[kvt][1], qf[t][qc][1], s[kvt], 0, 0, 0);
        }
        __builtin_amdgcn_s_setprio(0);

        if (kt == lim[t]) {
          int qg = qt[t] * 32 + qc * 16 + l15;
#pragma unroll
          for (int kvt = 0; kvt < 4; ++kvt)
#pragma unroll
            for (int j = 0; j < 4; ++j) {
              int kg = kt * 64 + kvt * 16 + l4 * 4 + j;
              if (kg > qg) s[kvt][j] = -1e30f;
            }
        }

#pragma unroll
        for (int kvt = 0; kvt < 4; ++kvt) {
          float p0 = exp2f(s[kvt][0]);
          float p1 = exp2f(s[kvt][1]);
          float p2 = exp2f(s[kvt][2]);
          float p3 = exp2f(s[kvt][3]);
          unsigned lo = cvt_pk_bf16(p0, p1);
          unsigned hi = cvt_pk_bf16(p2, p3);
          *(uint2v*)(pb + (qc * 16 + l15) * 72 + kvt * 16 + l4 * 4) = uint2v{lo, hi};
        }
      }
    }

    // single same-wave LDS drain for both tiles
    asm volatile("s_waitcnt lgkmcnt(0)" ::: "memory");

    // phase B: PV + l-sum for both tiles
    __builtin_amdgcn_s_setprio(1);
#pragma unroll
    for (int t = 0; t < 2; ++t) {
      bool act = (t == 0) ? act0 : act1;
      if (!act) continue;
      const short* pb = &P_lds[w][t][0];
#pragma unroll
      for (int qc = 0; qc < 2; ++qc)
#pragma unroll
        for (int kc = 0; kc < 2; ++kc) {
          short8 pf = *(const short8*)(pb + (qc * 16 + l15) * 72 + kc * 32 + l4 * 8);
          lacc[t][qc] = __builtin_amdgcn_mfma_f32_16x16x32_bf16(ONES, pf, lacc[t][qc], 0, 0, 0);
#pragma unroll
          for (int dt = 0; dt < 4; ++dt)
            o_[t][qc][dt] = __builtin_amdgcn_mfma_f32_16x16x32_bf16(vf[dt][kc], pf, o_[t][qc][dt], 0, 0, 0);
        }
    }
    __builtin_amdgcn_s_setprio(0);

    if (more) {
      *(short8*)&Kl[cur ^ 1][sr0 * 72 + sdc] = pre0;
      *(short8*)&Kl[cur ^ 1][sr1 * 72 + sdc] = pre1;
    }
    __syncthreads();
    cur ^= 1;
  }

#pragma unroll
  for (int t = 0; t < 2; ++t) {
#pragma unroll
    for (int qc = 0; qc < 2; ++qc) {
      float inv = 1.f / lacc[t][qc][0];
      size_t rowb = (size_t)(batch * T + qt[t] * 32 + qc * 16 + l15) * 1024 + h * 64;
#pragma unroll
      for (int dt = 0; dt < 4; ++dt) {
        short4v pk4;
#pragma unroll
        for (int j = 0; j < 4; ++j) pk4[j] = f2bf(o_[t][qc][dt][j] * inv);
        *(short4v*)(out + rowb + dt * 16 + l4 * 4) = pk4;
      }
    }
  }
}

extern "C" void kernel_launch(void* const* d_in, const int* in_sizes, int n_in,
                              void* d_out, int out_size, void* d_ws, size_t ws_size,
                              hipStream_t stream) {
  const float* x      = (const float*)d_in[0];
  const float* w_attn = (const float*)d_in[1];
  const float* b_attn = (const float*)d_in[2];
  const float* w_proj = (const float*)d_in[3];
  const float* b_proj = (const float*)d_in[4];
  float* out = (float*)d_out;

  char* ws = (char*)d_ws;
  short* xb   = (short*)(ws);                    // 16,777,216 B
  short* waT  = (short*)(ws + 16777216);         //  6,291,456 B
  short* wpT  = (short*)(ws + 23068672);         //  2,097,152 B
  short* qkv  = (short*)(ws + 25165824);         // 50,331,648 B
  short* vT   = (short*)(ws + 75497472);         // 16,777,216 B  (total 92,274,688)
  short* attn = xb;                              // xb dead after gemm1

  k_convert_bf16<<<4096, 256, 0, stream>>>(x, xb, 1048576);
  k_transpose_w<<<32 * 96, 256, 0, stream>>>(w_attn, waT, 1024, 3072);
  k_transpose_w<<<32 * 32, 256, 0, stream>>>(w_proj, wpT, 1024, 1024);
  k_gemm2ph256<true><<<384, 512, 0, stream>>>(xb, waT, b_attn, qkv, vT, 8192, 3072, 1024);
  k_attn<<<512, 256, 0, stream>>>(qkv, vT, attn);
  k_gemm8p<false><<<256, 512, 0, stream>>>(attn, wpT, b_proj, out, nullptr, 8192, 1024, 1024);
}

// Round 22
// 175.404 us; speedup vs baseline: 1.3076x; 1.0886x over previous
//
#include <hip/hip_runtime.h>

typedef short short8 __attribute__((ext_vector_type(8)));
typedef short short4v __attribute__((ext_vector_type(4)));
typedef float f32x4 __attribute__((ext_vector_type(4)));
typedef unsigned uint2v __attribute__((ext_vector_type(2)));

__device__ __forceinline__ float bf2f(short b) {
  unsigned u = ((unsigned)(unsigned short)b) << 16;
  return __builtin_bit_cast(float, u);
}
__device__ __forceinline__ short f2bf(float f) {
  unsigned u = __builtin_bit_cast(unsigned, f);
  u += 0x7fffu + ((u >> 16) & 1u);
  return (short)(u >> 16);
}
__device__ __forceinline__ unsigned cvt_pk_bf16(float lo, float hi) {
  unsigned r;
  asm("v_cvt_pk_bf16_f32 %0, %1, %2" : "=v"(r) : "v"(lo), "v"(hi));
  return r;
}

__device__ __forceinline__ void gload_lds16(const void* g, void* l) {
  __builtin_amdgcn_global_load_lds(
      (const __attribute__((address_space(1))) unsigned int*)g,
      (__attribute__((address_space(3))) unsigned int*)l, 16, 0, 0);
}

// swizzled LDS fragment read: tile rows of 64 shorts (128B), chunk = 16B unit,
// physical chunk = logical chunk ^ (row & 7)  [T2 involution]
__device__ __forceinline__ short8 lds_frag(const short* tile, int row, int kc, int l4) {
  int chunk = (kc * 4 + l4) ^ (row & 7);
  return *(const short8*)&tile[row * 64 + chunk * 8];
}

// ---------------- merged prep: fp32->bf16 convert (x) + both weight transposes ----------------
// blocks [0,4096): convert x (4096*256*8 = 8,388,608 f32 pairs -> exact, no bound check)
// blocks [4096,7168): transpose w_attn (K=1024, N=3072); blocks [7168,8192): w_proj (1024x1024)
__global__ __launch_bounds__(256) void k_prep(const float* __restrict__ x, short* __restrict__ xb,
                                              const float* __restrict__ w_attn, short* __restrict__ waT,
                                              const float* __restrict__ w_proj, short* __restrict__ wpT) {
  __shared__ float t[32][33];
  int b = blockIdx.x;
  if (b < 4096) {
    int i = b * 256 + threadIdx.x;
    const float4* p = (const float4*)x;
    float4 a = p[2 * i], c = p[2 * i + 1];
    short8 o;
    o[0] = f2bf(a.x); o[1] = f2bf(a.y); o[2] = f2bf(a.z); o[3] = f2bf(a.w);
    o[4] = f2bf(c.x); o[5] = f2bf(c.y); o[6] = f2bf(c.z); o[7] = f2bf(c.w);
    ((short8*)xb)[i] = o;
    return;
  }
  const float* w;
  short* wT;
  int blk, N;
  if (b < 7168) {
    w = w_attn; wT = waT; blk = b - 4096; N = 3072;
  } else {
    w = w_proj; wT = wpT; blk = b - 7168; N = 1024;
  }
  const int K = 1024;
  int nt = N >> 5;
  int rt = blk / nt, ct = blk % nt;
  int tx = threadIdx.x & 31, ty = threadIdx.x >> 5;
#pragma unroll
  for (int i = 0; i < 4; ++i) {
    int r = ty * 4 + i;
    t[r][tx] = w[(size_t)(rt * 32 + r) * N + ct * 32 + tx];
  }
  __syncthreads();
#pragma unroll
  for (int i = 0; i < 4; ++i) {
    int r = ty * 4 + i;
    wT[(size_t)(ct * 32 + r) * K + rt * 32 + tx] = f2bf(t[tx][r]);
  }
}

// ---------------- GEMM1 256x192, BK=64, TWO phases/K-tile (24 MFMA each) ----------------
// r18's verified 2-phase skeleton widened to BN=192: grid 512 = EXACTLY 2 rounds/CU
// (integral, like r18's 3 rounds) with 1.5x the MFMA per barrier-pair. Staging in 64-row
// groups (A: 4, B: 3), same linear-dest + pre-swizzled-source involution. Stagger preserved:
// A-hi(t+1)@ph1 -> buf b^1 (last reader ph2(t-1)); B(t+2)+A-lo(t+2)@ph2 -> buf b (last
// readers ph1(t)). FIFO: 7 loads/tile/wave -> steady vmcnt(7) both phase ends; prologue 12
// loads -> vmcnt(5); tails 0/2. LDS 112KB, ~180 VGPR, 8 waves = 2/SIMD at 1 block/CU.
// BF16OUT: cols >= 2048 (V part of qkv) written transposed into vT[bh][d][tok].
template <bool BF16OUT>
__global__ __launch_bounds__(512, 1) void k_gemm192(const short* __restrict__ A,
                                                    const short* __restrict__ Bt,
                                                    const float* __restrict__ bias,
                                                    void* __restrict__ Cout,
                                                    short* __restrict__ vTout,
                                                    int M, int N, int K) {
  __shared__ __align__(16) short Ab[2][256 * 64];
  __shared__ __align__(16) short Bb[2][192 * 64];
  int nt = N / 192;
  int nwg = gridDim.x;
  int bid = blockIdx.x;
  int swz = (bid & 7) * (nwg >> 3) + (bid >> 3);  // nwg % 8 == 0 -> bijective
  int mt = swz / nt, ct = swz % nt;
  int tid = threadIdx.x, w = tid >> 6, lane = tid & 63;
  int l15 = lane & 15, l4 = lane >> 4;
  int wm = w >> 2, wn = w & 3;
  const short* Abase = A + (size_t)mt * 256 * K;
  const short* Bbase = Bt + (size_t)ct * 192 * K;
  int NT = K >> 6;

  int srow = lane >> 3;
  int slc = (lane & 7) ^ srow;  // pre-swizzled source chunk (involution partner of read XOR)

  // stage one 64-row group: linear LDS dest, XOR-swizzled global source (1 issue/wave)
  auto stage64 = [&](const short* gbase, short* dstTile, int kt, int g) {
    int rowg = g * 64 + w * 8;
    gload_lds16(gbase + (size_t)(rowg + srow) * K + kt * 64 + slc * 8,
                dstTile + (size_t)rowg * 64);
  };

  f32x4 acc[8][3];
#pragma unroll
  for (int m = 0; m < 8; ++m)
#pragma unroll
    for (int n = 0; n < 3; ++n) acc[m][n] = f32x4{0.f, 0.f, 0.f, 0.f};

  // prologue: B0(3), A0(4), B1(3), A-lo1(2) = 12 loads; wait tile0's 7 -> vmcnt(5)
  stage64(Bbase, &Bb[0][0], 0, 0);
  stage64(Bbase, &Bb[0][0], 0, 1);
  stage64(Bbase, &Bb[0][0], 0, 2);
  stage64(Abase, &Ab[0][0], 0, 0);
  stage64(Abase, &Ab[0][0], 0, 1);
  stage64(Abase, &Ab[0][0], 0, 2);
  stage64(Abase, &Ab[0][0], 0, 3);
  stage64(Bbase, &Bb[1][0], 1, 0);
  stage64(Bbase, &Bb[1][0], 1, 1);
  stage64(Bbase, &Bb[1][0], 1, 2);
  stage64(Abase, &Ab[1][0], 1, 0);
  stage64(Abase, &Ab[1][0], 1, 1);
  asm volatile("s_waitcnt vmcnt(5)" ::: "memory");
  __builtin_amdgcn_s_barrier();

  for (int t = 0; t < NT; ++t) {
    int b = t & 1;
    const short* At = &Ab[b][0];
    const short* Btl = &Bb[b][0];
    bool p1 = (t + 1 < NT), p2 = (t + 2 < NT);

    short8 alo[4][2], ahi[4][2], bfr[3][2];

    // ===== phase 1: m-lo x n (B cached for ph2); stage A-hi(t+1) -> buf b^1 =====
#pragma unroll
    for (int mq = 0; mq < 4; ++mq)
#pragma unroll
      for (int kc = 0; kc < 2; ++kc)
        alo[mq][kc] = lds_frag(At, wm * 128 + mq * 16 + l15, kc, l4);
#pragma unroll
    for (int nq = 0; nq < 3; ++nq)
#pragma unroll
      for (int kc = 0; kc < 2; ++kc)
        bfr[nq][kc] = lds_frag(Btl, wn * 48 + nq * 16 + l15, kc, l4);
    if (p1) {
      stage64(Abase, &Ab[(t + 1) & 1][0], t + 1, 2);  // A-hi(t+1): last reader ph2(t-1)
      stage64(Abase, &Ab[(t + 1) & 1][0], t + 1, 3);
    }
    __builtin_amdgcn_s_barrier();
    asm volatile("s_waitcnt lgkmcnt(0)" ::: "memory");
    __builtin_amdgcn_sched_barrier(0);
    __builtin_amdgcn_s_setprio(1);
#pragma unroll
    for (int mq = 0; mq < 4; ++mq)
#pragma unroll
      for (int nq = 0; nq < 3; ++nq)
#pragma unroll
        for (int kc = 0; kc < 2; ++kc)
          acc[mq][nq] = __builtin_amdgcn_mfma_f32_16x16x32_bf16(alo[mq][kc], bfr[nq][kc], acc[mq][nq], 0, 0, 0);
    __builtin_amdgcn_s_setprio(0);
    // A-hi(t) (issued ph1(t-1)) must land; newer in flight: ph2(t-1)[5] + ph1(t)[2] = 7
    if (p1) {
      asm volatile("s_waitcnt vmcnt(7)" ::: "memory");
    } else {
      asm volatile("s_waitcnt vmcnt(0)" ::: "memory");
    }
    __builtin_amdgcn_s_barrier();  // ph1-end: all B + A-lo reads of tile t complete

    // ===== phase 2: m-hi x n (B from regs); stage B(t+2)+A-lo(t+2) -> buf b =====
#pragma unroll
    for (int mq = 0; mq < 4; ++mq)
#pragma unroll
      for (int kc = 0; kc < 2; ++kc)
        ahi[mq][kc] = lds_frag(At, wm * 128 + 64 + mq * 16 + l15, kc, l4);
    if (p2) {
      stage64(Bbase, &Bb[b][0], t + 2, 0);
      stage64(Bbase, &Bb[b][0], t + 2, 1);
      stage64(Bbase, &Bb[b][0], t + 2, 2);
      stage64(Abase, &Ab[b][0], t + 2, 0);
      stage64(Abase, &Ab[b][0], t + 2, 1);
    }
    __builtin_amdgcn_s_barrier();
    asm volatile("s_waitcnt lgkmcnt(0)" ::: "memory");
    __builtin_amdgcn_sched_barrier(0);
    __builtin_amdgcn_s_setprio(1);
#pragma unroll
    for (int mq = 0; mq < 4; ++mq)
#pragma unroll
      for (int nq = 0; nq < 3; ++nq)
#pragma unroll
        for (int kc = 0; kc < 2; ++kc)
          acc[4 + mq][nq] = __builtin_amdgcn_mfma_f32_16x16x32_bf16(ahi[mq][kc], bfr[nq][kc], acc[4 + mq][nq], 0, 0, 0);
    __builtin_amdgcn_s_setprio(0);
    // B(t+1)+A-lo(t+1) (issued ph2(t-1)) must land; newer: ph1(t)[2] + ph2(t)[5] = 7
    if (p2) {
      asm volatile("s_waitcnt vmcnt(7)" ::: "memory");
    } else if (p1) {
      asm volatile("s_waitcnt vmcnt(2)" ::: "memory");
    }
    __builtin_amdgcn_s_barrier();  // ph2-end: all A-hi reads of tile t complete
  }

  // epilogue
#pragma unroll
  for (int m = 0; m < 8; ++m) {
#pragma unroll
    for (int n = 0; n < 3; ++n) {
      int row = mt * 256 + wm * 128 + m * 16 + l4 * 4;
      int col = ct * 192 + wn * 48 + n * 16 + l15;
      float bv = bias[col];
      if constexpr (BF16OUT) {
        short4v pk4;
#pragma unroll
        for (int j = 0; j < 4; ++j) pk4[j] = f2bf(acc[m][n][j] + bv);
        if (col >= 2048) {
          int hh = (col - 2048) >> 6, dd = (col - 2048) & 63;
          int batch2 = row >> 11, tok = row & 2047;
          *(short4v*)(vTout + (((size_t)(batch2 * 16 + hh) * 64 + dd) << 11) + tok) = pk4;
        } else {
#pragma unroll
          for (int j = 0; j < 4; ++j)
            ((short*)Cout)[(size_t)(row + j) * N + col] = pk4[j];
        }
      } else {
#pragma unroll
        for (int j = 0; j < 4; ++j)
          ((float*)Cout)[(size_t)(row + j) * N + col] = acc[m][n][j] + bv;
      }
    }
  }
}

// ---------------- GEMM 256x128, BK=64, TWO phases/K-tile (16 MFMA each) [r18 verified] ----------------
template <bool BF16OUT>
__global__ __launch_bounds__(512, 1) void k_gemm8p(const short* __restrict__ A,
                                                   const short* __restrict__ Bt,
                                                   const float* __restrict__ bias,
                                                   void* __restrict__ Cout,
                                                   short* __restrict__ vTout,
                                                   int M, int N, int K) {
  __shared__ __align__(16) short Ab[2][256 * 64];
  __shared__ __align__(16) short Bb[2][128 * 64];
  int nt = N >> 7;
  int nwg = gridDim.x;
  int bid = blockIdx.x;
  int swz = (bid & 7) * (nwg >> 3) + (bid >> 3);
  int mt = swz / nt, ct = swz % nt;
  int tid = threadIdx.x, w = tid >> 6, lane = tid & 63;
  int l15 = lane & 15, l4 = lane >> 4;
  int wm = w >> 2, wn = w & 3;
  const short* Abase = A + (size_t)mt * 256 * K;
  const short* Bbase = Bt + (size_t)ct * 128 * K;
  int NT = K >> 6;

  int srow = lane >> 3;
  int slc = (lane & 7) ^ srow;

  auto stage = [&](const short* gbase, short* dstTile, int kt, int half) {
#pragma unroll
    for (int i = 0; i < 2; ++i) {
      int rowg = half * 128 + i * 64 + w * 8;
      gload_lds16(gbase + (size_t)(rowg + srow) * K + kt * 64 + slc * 8,
                  dstTile + (size_t)rowg * 64);
    }
  };

  f32x4 acc[8][2];
#pragma unroll
  for (int m = 0; m < 8; ++m)
#pragma unroll
    for (int n = 0; n < 2; ++n) acc[m][n] = f32x4{0.f, 0.f, 0.f, 0.f};

  stage(Bbase, &Bb[0][0], 0, 0);
  stage(Abase, &Ab[0][0], 0, 0);
  stage(Abase, &Ab[0][0], 0, 1);
  stage(Bbase, &Bb[1][0], 1, 0);
  stage(Abase, &Ab[1][0], 1, 0);
  asm volatile("s_waitcnt vmcnt(6)" ::: "memory");
  __builtin_amdgcn_s_barrier();

  for (int t = 0; t < NT; ++t) {
    int b = t & 1;
    const short* At = &Ab[b][0];
    const short* Btl = &Bb[b][0];
    bool p1 = (t + 1 < NT), p2 = (t + 2 < NT);

    short8 alo[4][2], ahi[4][2], bfr[2][2];

#pragma unroll
    for (int mq = 0; mq < 4; ++mq)
#pragma unroll
      for (int kc = 0; kc < 2; ++kc)
        alo[mq][kc] = lds_frag(At, wm * 128 + mq * 16 + l15, kc, l4);
#pragma unroll
    for (int n = 0; n < 2; ++n)
#pragma unroll
      for (int kc = 0; kc < 2; ++kc)
        bfr[n][kc] = lds_frag(Btl, wn * 32 + n * 16 + l15, kc, l4);
    if (p1) stage(Abase, &Ab[(t + 1) & 1][0], t + 1, 1);
    __builtin_amdgcn_s_barrier();
    asm volatile("s_waitcnt lgkmcnt(0)" ::: "memory");
    __builtin_amdgcn_sched_barrier(0);
    __builtin_amdgcn_s_setprio(1);
#pragma unroll
    for (int mq = 0; mq < 4; ++mq)
#pragma unroll
      for (int n = 0; n < 2; ++n)
#pragma unroll
        for (int kc = 0; kc < 2; ++kc)
          acc[mq][n] = __builtin_amdgcn_mfma_f32_16x16x32_bf16(alo[mq][kc], bfr[n][kc], acc[mq][n], 0, 0, 0);
    __builtin_amdgcn_s_setprio(0);
    if (p1) {
      asm volatile("s_waitcnt vmcnt(6)" ::: "memory");
    } else {
      asm volatile("s_waitcnt vmcnt(0)" ::: "memory");
    }
    __builtin_amdgcn_s_barrier();

#pragma unroll
    for (int mq = 0; mq < 4; ++mq)
#pragma unroll
      for (int kc = 0; kc < 2; ++kc)
        ahi[mq][kc] = lds_frag(At, wm * 128 + 64 + mq * 16 + l15, kc, l4);
    if (p2) {
      stage(Bbase, &Bb[b][0], t + 2, 0);
      stage(Abase, &Ab[b][0], t + 2, 0);
    }
    __builtin_amdgcn_s_barrier();
    asm volatile("s_waitcnt lgkmcnt(0)" ::: "memory");
    __builtin_amdgcn_sched_barrier(0);
    __builtin_amdgcn_s_setprio(1);
#pragma unroll
    for (int mq = 0; mq < 4; ++mq)
#pragma unroll
      for (int n = 0; n < 2; ++n)
#pragma unroll
        for (int kc = 0; kc < 2; ++kc)
          acc[4 + mq][n] = __builtin_amdgcn_mfma_f32_16x16x32_bf16(ahi[mq][kc], bfr[n][kc], acc[4 + mq][n], 0, 0, 0);
    __builtin_amdgcn_s_setprio(0);
    if (p2) {
      asm volatile("s_waitcnt vmcnt(6)" ::: "memory");
    } else if (p1) {
      asm volatile("s_waitcnt vmcnt(2)" ::: "memory");
    }
    __builtin_amdgcn_s_barrier();
  }

#pragma unroll
  for (int m = 0; m < 8; ++m) {
#pragma unroll
    for (int n = 0; n < 2; ++n) {
      int row = mt * 256 + wm * 128 + m * 16 + l4 * 4;
      int col = ct * 128 + wn * 32 + n * 16 + l15;
      float bv = bias[col];
      if constexpr (BF16OUT) {
        short4v pk4;
#pragma unroll
        for (int j = 0; j < 4; ++j) pk4[j] = f2bf(acc[m][n][j] + bv);
        if (col >= 2048) {
          int hh = (col - 2048) >> 6, dd = (col - 2048) & 63;
          int batch2 = row >> 11, tok = row & 2047;
          *(short4v*)(vTout + (((size_t)(batch2 * 16 + hh) * 64 + dd) << 11) + tok) = pk4;
        } else {
#pragma unroll
          for (int j = 0; j < 4; ++j)
            ((short*)Cout)[(size_t)(row + j) * N + col] = pk4[j];
        }
      } else {
#pragma unroll
        for (int j = 0; j < 4; ++j)
          ((float*)Cout)[(size_t)(row + j) * N + col] = acc[m][n][j] + bv;
      }
    }
  }
}

// ---------------- fused causal attention (r16/r18 structure, verified 83us) ----------------
__global__ __launch_bounds__(256, 2) void k_attn(const short* __restrict__ qkv,
                                                 const short* __restrict__ vT,
                                                 short* __restrict__ out) {
  constexpr int T = 2048, C3 = 3072;
  __shared__ __align__(16) short Kl[2][64 * 72];
  __shared__ __align__(16) short P_lds[4][2][32 * 72];
  int i_ = blockIdx.x;
  int xcd = i_ & 7, m_ = i_ >> 3;
  int bh = xcd * 8 + (m_ & 7), bp = m_ >> 3;
  int batch = bh >> 4, h = bh & 15;
  int tid = threadIdx.x, w = tid >> 6, lane = tid & 63;
  int l15 = lane & 15, l4 = lane >> 4;

  int qt[2];
  qt[0] = 63 - (bp * 4 + w);
  qt[1] = bp * 4 + w;
  int lim[2] = {qt[0] >> 1, qt[1] >> 1};
  int ktb = (63 - bp * 4) >> 1;

  const short* kbase = qkv + (size_t)(batch * T) * C3 + 1024 + h * 64;
  const short* vbase = vT + (size_t)bh * 64 * T;

  int sr0 = tid >> 3, sr1 = 32 + (tid >> 3), sdc = (tid & 7) * 8;

  const float SCL = 0.18033688f;
  short8 qf[2][2][2];
#pragma unroll
  for (int t = 0; t < 2; ++t)
#pragma unroll
    for (int qc = 0; qc < 2; ++qc) {
      const short* qrow = qkv + (size_t)(batch * T + qt[t] * 32 + qc * 16 + l15) * C3 + h * 64;
#pragma unroll
      for (int kc = 0; kc < 2; ++kc) {
        short8 v = *(const short8*)(qrow + kc * 32 + l4 * 8);
#pragma unroll
        for (int i = 0; i < 8; ++i) v[i] = f2bf(bf2f(v[i]) * SCL);
        qf[t][qc][kc] = v;
      }
    }

  const f32x4 ZERO = f32x4{0.f, 0.f, 0.f, 0.f};
  short8 ONES;
#pragma unroll
  for (int i = 0; i < 8; ++i) ONES[i] = (short)0x3F80;  // bf16 1.0

  f32x4 o_[2][2][4];
  f32x4 lacc[2][2];
#pragma unroll
  for (int t = 0; t < 2; ++t)
#pragma unroll
    for (int qc = 0; qc < 2; ++qc) {
      lacc[t][qc] = ZERO;
#pragma unroll
      for (int dt = 0; dt < 4; ++dt) o_[t][qc][dt] = ZERO;
    }

  {
    short8 a = *(const short8*)(kbase + (size_t)sr0 * C3 + sdc);
    short8 b = *(const short8*)(kbase + (size_t)sr1 * C3 + sdc);
    *(short8*)&Kl[0][sr0 * 72 + sdc] = a;
    *(short8*)&Kl[0][sr1 * 72 + sdc] = b;
  }
  __syncthreads();

  int cur = 0;
  for (int kt = 0; kt <= ktb; ++kt) {
    bool more = (kt < ktb);
    bool act0 = (kt <= lim[0]), act1 = (kt <= lim[1]);

    short8 pre0, pre1;
    if (more) {
      pre0 = *(const short8*)(kbase + (size_t)((kt + 1) * 64 + sr0) * C3 + sdc);
      pre1 = *(const short8*)(kbase + (size_t)((kt + 1) * 64 + sr1) * C3 + sdc);
    }

    const short* Kb = &Kl[cur][0];
    short8 kf[4][2];
#pragma unroll
    for (int kvt = 0; kvt < 4; ++kvt)
#pragma unroll
      for (int kc = 0; kc < 2; ++kc)
        kf[kvt][kc] = *(const short8*)(Kb + (kvt * 16 + l15) * 72 + kc * 32 + l4 * 8);

    short8 vf[4][2];
#pragma unroll
    for (int dt = 0; dt < 4; ++dt)
#pragma unroll
      for (int kc = 0; kc < 2; ++kc)
        vf[dt][kc] = *(const short8*)(vbase + (size_t)(dt * 16 + l15) * T + kt * 64 + kc * 32 + l4 * 8);

    // phase A: QK + mask + softmax + pack for BOTH tiles (independent chains)
#pragma unroll
    for (int t = 0; t < 2; ++t) {
      bool act = (t == 0) ? act0 : act1;
      if (!act) continue;
      short* pb = &P_lds[w][t][0];

#pragma unroll
      for (int qc = 0; qc < 2; ++qc) {
        f32x4 s[4];
        __builtin_amdgcn_s_setprio(1);
#pragma unroll
        for (int kvt = 0; kvt < 4; ++kvt) {
          s[kvt] = __builtin_amdgcn_mfma_f32_16x16x32_bf16(kf[kvt][0], qf[t][qc][0], ZERO, 0, 0, 0);
          s[kvt] = __builtin_amdgcn_mfma_f32_16x16x32_bf16(kf[kvt][1], qf[t][qc][1], s[kvt], 0, 0, 0);
        }
        __builtin_amdgcn_s_setprio(0);

        if (kt == lim[t]) {
          int qg = qt[t] * 32 + qc * 16 + l15;
#pragma unroll
          for (int kvt = 0; kvt < 4; ++kvt)
#pragma unroll
            for (int j = 0; j < 4; ++j) {
              int kg = kt * 64 + kvt * 16 + l4 * 4 + j;
              if (kg > qg) s[kvt][j] = -1e30f;
            }
        }

#pragma unroll
        for (int kvt = 0; kvt < 4; ++kvt) {
          float p0 = exp2f(s[kvt][0]);
          float p1 = exp2f(s[kvt][1]);
          float p2 = exp2f(s[kvt][2]);
          float p3 = exp2f(s[kvt][3]);
          unsigned lo = cvt_pk_bf16(p0, p1);
          unsigned hi = cvt_pk_bf16(p2, p3);
          *(uint2v*)(pb + (qc * 16 + l15) * 72 + kvt * 16 + l4 * 4) = uint2v{lo, hi};
        }
      }
    }

    // single same-wave LDS drain for both tiles
    asm volatile("s_waitcnt lgkmcnt(0)" ::: "memory");

    // phase B: PV + l-sum for both tiles
    __builtin_amdgcn_s_setprio(1);
#pragma unroll
    for (int t = 0; t < 2; ++t) {
      bool act = (t == 0) ? act0 : act1;
      if (!act) continue;
      const short* pb = &P_lds[w][t][0];
#pragma unroll
      for (int qc = 0; qc < 2; ++qc)
#pragma unroll
        for (int kc = 0; kc < 2; ++kc) {
          short8 pf = *(const short8*)(pb + (qc * 16 + l15) * 72 + kc * 32 + l4 * 8);
          lacc[t][qc] = __builtin_amdgcn_mfma_f32_16x16x32_bf16(ONES, pf, lacc[t][qc], 0, 0, 0);
#pragma unroll
          for (int dt = 0; dt < 4; ++dt)
            o_[t][qc][dt] = __builtin_amdgcn_mfma_f32_16x16x32_bf16(vf[dt][kc], pf, o_[t][qc][dt], 0, 0, 0);
        }
    }
    __builtin_amdgcn_s_setprio(0);

    if (more) {
      *(short8*)&Kl[cur ^ 1][sr0 * 72 + sdc] = pre0;
      *(short8*)&Kl[cur ^ 1][sr1 * 72 + sdc] = pre1;
    }
    __syncthreads();
    cur ^= 1;
  }

#pragma unroll
  for (int t = 0; t < 2; ++t) {
#pragma unroll
    for (int qc = 0; qc < 2; ++qc) {
      float inv = 1.f / lacc[t][qc][0];
      size_t rowb = (size_t)(batch * T + qt[t] * 32 + qc * 16 + l15) * 1024 + h * 64;
#pragma unroll
      for (int dt = 0; dt < 4; ++dt) {
        short4v pk4;
#pragma unroll
        for (int j = 0; j < 4; ++j) pk4[j] = f2bf(o_[t][qc][dt][j] * inv);
        *(short4v*)(out + rowb + dt * 16 + l4 * 4) = pk4;
      }
    }
  }
}

extern "C" void kernel_launch(void* const* d_in, const int* in_sizes, int n_in,
                              void* d_out, int out_size, void* d_ws, size_t ws_size,
                              hipStream_t stream) {
  const float* x      = (const float*)d_in[0];
  const float* w_attn = (const float*)d_in[1];
  const float* b_attn = (const float*)d_in[2];
  const float* w_proj = (const float*)d_in[3];
  const float* b_proj = (const float*)d_in[4];
  float* out = (float*)d_out;

  char* ws = (char*)d_ws;
  short* xb   = (short*)(ws);                    // 16,777,216 B
  short* waT  = (short*)(ws + 16777216);         //  6,291,456 B
  short* wpT  = (short*)(ws + 23068672);         //  2,097,152 B
  short* qkv  = (short*)(ws + 25165824);         // 50,331,648 B
  short* vT   = (short*)(ws + 75497472);         // 16,777,216 B  (total 92,274,688)
  short* attn = xb;                              // xb dead after gemm1

  k_prep<<<8192, 256, 0, stream>>>(x, xb, w_attn, waT, w_proj, wpT);
  k_gemm192<true><<<512, 512, 0, stream>>>(xb, waT, b_attn, qkv, vT, 8192, 3072, 1024);
  k_attn<<<512, 256, 0, stream>>>(qkv, vT, attn);
  k_gemm8p<false><<<256, 512, 0, stream>>>(attn, wpT, b_proj, out, nullptr, 8192, 1024, 1024);
}